// Round 1
// baseline (347.312 us; speedup 1.0000x reference)
//
#include <hip/hip_runtime.h>
#include <hip/hip_bf16.h>

// Decoder: x = z @ softplus(W_mix)^T ; per-channel MLP 1->H->H->1 with tanh.
// N=16384 samples, L=16 latent, D=128 channels, H=64 hidden.
// Round 1: correct fp32 vector-ALU baseline. One block per (d, 256-sample
// tile); W2[d] staged in LDS; inner matvec reads LDS rows via ds_read_b128
// (wave-uniform -> broadcast). fp32 FMA roofline ~109us; predicted ~140us.

#define N_SAMPLES 16384
#define L_DIM 16
#define D_DIM 128
#define H_DIM 64

__device__ __forceinline__ float fast_tanh(float x) {
    // tanh(x) = 1 - 2/(1+exp(2x)); stable: x->+inf => 1, x->-inf => -1
    float e = __expf(2.0f * x);
    return 1.0f - 2.0f * __builtin_amdgcn_rcpf(1.0f + e);
}

__global__ __launch_bounds__(256, 2) void decoder_fp32(
    const float* __restrict__ z,
    const float* __restrict__ W_mix,
    const float* __restrict__ W1,
    const float* __restrict__ b1,
    const float* __restrict__ W2,
    const float* __restrict__ b2,
    const float* __restrict__ W3,
    const float* __restrict__ b3,
    float* __restrict__ out)
{
    const int d   = blockIdx.x;        // channel 0..127
    const int tid = threadIdx.x;       // 0..255
    const int n   = blockIdx.y * 256 + tid;

    __shared__ float s_mix[L_DIM];
    __shared__ float s_W1[H_DIM];
    __shared__ float s_b1[H_DIM];
    __shared__ float s_W2[H_DIM][H_DIM];   // [h][k], 16 KB
    __shared__ float s_b2[H_DIM];
    __shared__ float s_W3[H_DIM];
    __shared__ float s_b3;

    // ---- cooperative staging ----
    if (tid < L_DIM) {
        float w = W_mix[d * L_DIM + tid];
        s_mix[tid] = (w > 20.0f) ? w : log1pf(__expf(w));   // softplus
    }
    if (tid >= 64 && tid < 128) {
        int h = tid - 64;
        s_W1[h] = W1[d * H_DIM + h];
        s_b1[h] = b1[d * H_DIM + h];
    }
    if (tid >= 128 && tid < 192) {
        int h = tid - 128;
        s_b2[h] = b2[d * H_DIM + h];
        s_W3[h] = W3[d * H_DIM + h];
    }
    if (tid == 192) s_b3 = b3[d];
    {
        const float4* gW2 = (const float4*)(W2 + (size_t)d * H_DIM * H_DIM);
        float4* sW2 = (float4*)(&s_W2[0][0]);
        #pragma unroll
        for (int i = 0; i < 4; ++i) sW2[tid + i * 256] = gW2[tid + i * 256];
    }
    __syncthreads();

    // ---- x[n,d] = sum_l z[n,l] * softplus(W_mix[d,l]) ----
    const float4* zv = (const float4*)(z + (size_t)n * L_DIM);
    float x = 0.0f;
    #pragma unroll
    for (int i = 0; i < 4; ++i) {
        float4 zz = zv[i];
        x += zz.x * s_mix[4*i+0] + zz.y * s_mix[4*i+1]
           + zz.z * s_mix[4*i+2] + zz.w * s_mix[4*i+3];
    }

    // ---- layer 2 accumulators ----
    float acc[H_DIM];
    #pragma unroll
    for (int k = 0; k < H_DIM; ++k) acc[k] = s_b2[k];

    // ---- h-loop: h1 computed on the fly, rank-1 update into acc[64] ----
    #pragma unroll 1
    for (int h = 0; h < H_DIM; ++h) {
        float h1 = fast_tanh(x * s_W1[h] + s_b1[h]);
        const float4* row = (const float4*)(&s_W2[h][0]);
        #pragma unroll
        for (int kq = 0; kq < H_DIM / 4; ++kq) {
            float4 w = row[kq];
            acc[4*kq+0] += h1 * w.x;
            acc[4*kq+1] += h1 * w.y;
            acc[4*kq+2] += h1 * w.z;
            acc[4*kq+3] += h1 * w.w;
        }
    }

    // ---- layer 3: out = tanh(acc) . W3 + b3 ----
    float o = s_b3;
    #pragma unroll
    for (int k = 0; k < H_DIM; ++k) o += fast_tanh(acc[k]) * s_W3[k];

    out[(size_t)n * D_DIM + d] = o;
}

extern "C" void kernel_launch(void* const* d_in, const int* in_sizes, int n_in,
                              void* d_out, int out_size, void* d_ws, size_t ws_size,
                              hipStream_t stream) {
    const float* z     = (const float*)d_in[0];
    const float* W_mix = (const float*)d_in[1];
    const float* W1    = (const float*)d_in[2];
    const float* b1    = (const float*)d_in[3];
    const float* W2    = (const float*)d_in[4];
    const float* b2    = (const float*)d_in[5];
    const float* W3    = (const float*)d_in[6];
    const float* b3    = (const float*)d_in[7];
    float* out = (float*)d_out;

    dim3 grid(D_DIM, N_SAMPLES / 256);
    decoder_fp32<<<grid, dim3(256), 0, stream>>>(z, W_mix, W1, b1, W2, b2, W3, b3, out);
}

// Round 2
// 163.954 us; speedup vs baseline: 2.1184x; 2.1184x over previous
//
#include <hip/hip_runtime.h>
#include <hip/hip_bf16.h>

// Decoder: x = z @ softplus(W_mix)^T ; per-channel MLP 1->H->H->1 with tanh.
// N=16384, L=16, D=128, H=64.
// Round 2: bf16 MFMA for the H x H layer. Block = (channel d, 256-row tile),
// 4 waves, each wave computes a 64x64 tile of H2 via mfma_f32_16x16x32_bf16.
// Layer-1 h1 is computed straight into A-fragment registers (no LDS h1).
// W2^T staged in LDS bf16 (stride 72 = 144B keeps b128 alignment, 2-way max).
// Epilogue: tanh(acc+b2)*W3, shfl_xor butterfly row-reduce, predicated stores.

#define N_SAMPLES 16384
#define L_DIM 16
#define D_DIM 128
#define H_DIM 64
#define W2T_STRIDE 72   // ushort elems; 144 B: multiple of 16 B, 36 banks

typedef __attribute__((ext_vector_type(8))) short short8;
typedef __attribute__((ext_vector_type(4))) float float4v;

__device__ __forceinline__ float fast_tanh(float x) {
    // tanh(x) = 1 - 2/(1+exp(2x)); stable at +/-inf
    float e = __expf(2.0f * x);
    return 1.0f - 2.0f * __builtin_amdgcn_rcpf(1.0f + e);
}

__device__ __forceinline__ unsigned short f2bf(float f) {
    union { float f; unsigned int u; } v; v.f = f;
    unsigned int r = (v.u + 0x7fffu + ((v.u >> 16) & 1u)) >> 16;   // RNE
    return (unsigned short)r;
}

__global__ __launch_bounds__(256, 2) void decoder_mfma(
    const float* __restrict__ z,
    const float* __restrict__ W_mix,
    const float* __restrict__ W1,
    const float* __restrict__ b1,
    const float* __restrict__ W2,
    const float* __restrict__ b2,
    const float* __restrict__ W3,
    const float* __restrict__ b3,
    float* __restrict__ out)
{
    const int d      = blockIdx.x;          // channel
    const int tid    = threadIdx.x;         // 0..255
    const int lane   = tid & 63;
    const int waveId = tid >> 6;
    const int quad   = lane >> 4;
    const int l15    = lane & 15;
    const int nBase  = blockIdx.y * 256;

    __shared__ float s_mix[L_DIM];
    __shared__ __align__(16) float s_W1[H_DIM];
    __shared__ __align__(16) float s_b1[H_DIM];
    __shared__ float s_b2[H_DIM];
    __shared__ float s_W3[H_DIM];
    __shared__ float s_b3;
    __shared__ __align__(16) unsigned short s_w2t[H_DIM * W2T_STRIDE]; // [col][h]

    // ---- staging ----
    if (tid < L_DIM) {
        float w = W_mix[d * L_DIM + tid];
        s_mix[tid] = (w > 20.0f) ? w : log1pf(__expf(w));
    } else if (tid >= 64 && tid < 128) {
        int h = tid - 64;
        s_W1[h] = W1[d * H_DIM + h];
        s_b1[h] = b1[d * H_DIM + h];
    } else if (tid >= 128 && tid < 192) {
        int h = tid - 128;
        s_b2[h] = b2[d * H_DIM + h];
        s_W3[h] = W3[d * H_DIM + h];
    } else if (tid == 192) {
        s_b3 = b3[d];
    }
    {
        const float* gW2 = W2 + (size_t)d * H_DIM * H_DIM;   // [h][kout]
        #pragma unroll
        for (int i = 0; i < 16; ++i) {
            int idx = tid + i * 256;
            int h = idx >> 6, c = idx & 63;
            s_w2t[c * W2T_STRIDE + h] = f2bf(gW2[idx]);      // transpose
        }
    }
    __syncthreads();

    // ---- x[n] = z[n,:] . softplus(W_mix[d,:]) (thread t -> row t) ----
    const float4* zv = (const float4*)(z + (size_t)(nBase + tid) * L_DIM);
    float x = 0.0f;
    #pragma unroll
    for (int i = 0; i < 4; ++i) {
        float4 zz = zv[i];
        x += zz.x * s_mix[4*i+0] + zz.y * s_mix[4*i+1]
           + zz.z * s_mix[4*i+2] + zz.w * s_mix[4*i+3];
    }

    // x values for the 4 m-tiles this lane feeds: rows mt*16 + (lane&15)
    float xm[4];
    #pragma unroll
    for (int mt = 0; mt < 4; ++mt) xm[mt] = __shfl(x, mt * 16 + l15, 64);

    // ---- layer 1 directly into A fragments: A[m=lane&15][k=quad*8+j] ----
    short8 afrag[4][2];   // [mtile][kstep]
    #pragma unroll
    for (int ks = 0; ks < 2; ++ks) {
        float w1v[8], b1v[8];
        #pragma unroll
        for (int j = 0; j < 8; ++j) {
            int k = ks * 32 + quad * 8 + j;
            w1v[j] = s_W1[k];
            b1v[j] = s_b1[k];
        }
        #pragma unroll
        for (int mt = 0; mt < 4; ++mt) {
            short8 f;
            #pragma unroll
            for (int j = 0; j < 8; ++j) {
                float hv = fast_tanh(xm[mt] * w1v[j] + b1v[j]);
                f[j] = (short)f2bf(hv);
            }
            afrag[mt][ks] = f;
        }
    }

    // ---- B fragments: B[k=quad*8+j][n=lane&15] from s_w2t[col][h] ----
    short8 bfrag[4][2];   // [ntile][kstep]
    #pragma unroll
    for (int nt = 0; nt < 4; ++nt) {
        #pragma unroll
        for (int ks = 0; ks < 2; ++ks) {
            const short8* p = (const short8*)
                &s_w2t[(nt * 16 + l15) * W2T_STRIDE + ks * 32 + quad * 8];
            bfrag[nt][ks] = *p;
        }
    }

    // ---- MFMA: 4x4 tiles of 16x16, K=64 in two steps ----
    float4v acc[4][4];
    #pragma unroll
    for (int mt = 0; mt < 4; ++mt) {
        #pragma unroll
        for (int nt = 0; nt < 4; ++nt) {
            float4v c = {0.0f, 0.0f, 0.0f, 0.0f};
            c = __builtin_amdgcn_mfma_f32_16x16x32_bf16(afrag[mt][0], bfrag[nt][0], c, 0, 0, 0);
            c = __builtin_amdgcn_mfma_f32_16x16x32_bf16(afrag[mt][1], bfrag[nt][1], c, 0, 0, 0);
            acc[mt][nt] = c;
        }
    }

    // ---- epilogue: out[row] = sum_col tanh(acc+b2[col]) * W3[col] + b3 ----
    float w3v[4], b2v[4];
    #pragma unroll
    for (int nt = 0; nt < 4; ++nt) {
        int col = nt * 16 + l15;
        w3v[nt] = s_W3[col];
        b2v[nt] = s_b2[col];
    }

    float psum[4][4];   // [mtile][reg]; row = mt*16 + quad*4 + reg
    #pragma unroll
    for (int mt = 0; mt < 4; ++mt)
        #pragma unroll
        for (int r = 0; r < 4; ++r) psum[mt][r] = 0.0f;

    #pragma unroll
    for (int mt = 0; mt < 4; ++mt)
        #pragma unroll
        for (int nt = 0; nt < 4; ++nt)
            #pragma unroll
            for (int r = 0; r < 4; ++r)
                psum[mt][r] += fast_tanh(acc[mt][nt][r] + b2v[nt]) * w3v[nt];

    // butterfly reduce across the 16 column-lanes (lane bits 0..3)
    #pragma unroll
    for (int mask = 1; mask < 16; mask <<= 1)
        #pragma unroll
        for (int mt = 0; mt < 4; ++mt)
            #pragma unroll
            for (int r = 0; r < 4; ++r)
                psum[mt][r] += __shfl_xor(psum[mt][r], mask, 64);

    // store: lane with (lane&15) == mt*4+r writes row = mt*16 + quad*4 + r
    const float bias = s_b3;
    #pragma unroll
    for (int mt = 0; mt < 4; ++mt)
        #pragma unroll
        for (int r = 0; r < 4; ++r)
            if (l15 == mt * 4 + r) {
                int row = mt * 16 + quad * 4 + r;
                int n = nBase + waveId * 64 + row;
                out[(size_t)n * D_DIM + d] = psum[mt][r] + bias;
            }
}

extern "C" void kernel_launch(void* const* d_in, const int* in_sizes, int n_in,
                              void* d_out, int out_size, void* d_ws, size_t ws_size,
                              hipStream_t stream) {
    const float* z     = (const float*)d_in[0];
    const float* W_mix = (const float*)d_in[1];
    const float* W1    = (const float*)d_in[2];
    const float* b1    = (const float*)d_in[3];
    const float* W2    = (const float*)d_in[4];
    const float* b2    = (const float*)d_in[5];
    const float* W3    = (const float*)d_in[6];
    const float* b3    = (const float*)d_in[7];
    float* out = (float*)d_out;

    dim3 grid(D_DIM, N_SAMPLES / 256);
    decoder_mfma<<<grid, dim3(256), 0, stream>>>(z, W_mix, W1, b1, W2, b2, W3, b3, out);
}

// Round 3
// 160.607 us; speedup vs baseline: 2.1625x; 1.0208x over previous
//
#include <hip/hip_runtime.h>
#include <hip/hip_bf16.h>

// Decoder: x = z @ softplus(W_mix)^T ; per-channel MLP 1->H->H->1 with tanh.
// N=16384, L=16, D=128, H=64.
// Round 3: tanh via LDS lookup table (4096 cell-centered entries on [-4,4]).
// Round-2 post-mortem showed transcendentals issue at ~16 cyc/wave64 ->
// each exp+rcp tanh = ~38 issue cycles; 128 tanh/lane = ~70% of VALU time.
// Table lookup = ~10 cyc (fma + med3 + cvt + lshl + ds_read). Layer-1 table
// stores PRE-CONVERTED bf16 bits (kills all f2bf in the hot path); layer-2
// table stores f32. Index scale/offset folded into staged W1/b1/b2.
// Tables built by a tiny kernel into d_ws (fallback: in-block build).

#define N_SAMPLES 16384
#define L_DIM 16
#define D_DIM 128
#define H_DIM 64
#define W2T_STRIDE 72    // ushort elems; 144 B: 16B-aligned rows
#define TAB_N 4096       // [-4,4], step 1/512

typedef __attribute__((ext_vector_type(8))) short short8;
typedef __attribute__((ext_vector_type(4))) float float4v;

__device__ __forceinline__ float fast_tanh(float x) {
    float e = __expf(2.0f * x);
    return 1.0f - 2.0f * __builtin_amdgcn_rcpf(1.0f + e);
}

__device__ __forceinline__ unsigned short f2bf(float f) {
    union { float f; unsigned int u; } v; v.f = f;
    unsigned int r = (v.u + 0x7fffu + ((v.u >> 16) & 1u)) >> 16;   // RNE
    return (unsigned short)r;
}

// ---- table builder: ws[0..4095] = f32 tanh table, then 4096 u16 bf16 ----
__global__ void build_tables(float* __restrict__ ws) {
    int i = blockIdx.x * 256 + threadIdx.x;          // 0..4095
    float c = ((float)(i - 2048) + 0.5f) * (1.0f / 512.0f);
    float v = tanhf(c);
    ws[i] = v;
    ((unsigned short*)(ws + TAB_N))[i] = f2bf(v);
}

__global__ __launch_bounds__(256, 2) void decoder_mfma(
    const float* __restrict__ z,
    const float* __restrict__ W_mix,
    const float* __restrict__ W1,
    const float* __restrict__ b1,
    const float* __restrict__ W2,
    const float* __restrict__ b2,
    const float* __restrict__ W3,
    const float* __restrict__ b3,
    float* __restrict__ out,
    const float* __restrict__ tab_src)   // nullptr -> build in-block
{
    const int d      = blockIdx.x;
    const int tid    = threadIdx.x;
    const int lane   = tid & 63;
    const int waveId = tid >> 6;
    const int quad   = lane >> 4;
    const int l15    = lane & 15;
    const int nBase  = blockIdx.y * 256;

    __shared__ float s_mix[L_DIM];
    __shared__ __align__(16) float s_w1s[H_DIM];   // 512*W1
    __shared__ __align__(16) float s_b1s[H_DIM];   // 512*b1 + 2048
    __shared__ float s_c2[H_DIM];                  // 512*b2 + 2048
    __shared__ float s_W3[H_DIM];
    __shared__ float s_b3;
    __shared__ __align__(16) unsigned short s_w2t[H_DIM * W2T_STRIDE]; // [col][h]
    __shared__ __align__(16) float s_tabf[TAB_N];          // 16 KB
    __shared__ __align__(16) unsigned short s_tabh[TAB_N]; // 8 KB, bf16 bits

    // ---- stage tanh tables ----
    if (tab_src) {
        const float4* g4 = (const float4*)tab_src;
        float4* sf4 = (float4*)s_tabf;                 // 1024 float4
        #pragma unroll
        for (int i = 0; i < 4; ++i) sf4[tid + 256 * i] = g4[tid + 256 * i];
        const float4* g4h = (const float4*)(tab_src + TAB_N);
        float4* sh4 = (float4*)s_tabh;                 // 512 float4
        #pragma unroll
        for (int i = 0; i < 2; ++i) sh4[tid + 256 * i] = g4h[tid + 256 * i];
    } else {
        for (int i = tid; i < TAB_N; i += 256) {
            float c = ((float)(i - 2048) + 0.5f) * (1.0f / 512.0f);
            float v = fast_tanh(c);
            s_tabf[i] = v;
            s_tabh[i] = f2bf(v);
        }
    }

    // ---- stage small params (scale/offset folded for table indexing) ----
    if (tid < L_DIM) {
        float w = W_mix[d * L_DIM + tid];
        s_mix[tid] = (w > 20.0f) ? w : log1pf(__expf(w));
    } else if (tid >= 64 && tid < 128) {
        int h = tid - 64;
        s_w1s[h] = W1[d * H_DIM + h] * 512.0f;
        s_b1s[h] = b1[d * H_DIM + h] * 512.0f + 2048.0f;
    } else if (tid >= 128 && tid < 192) {
        int h = tid - 128;
        s_c2[h] = b2[d * H_DIM + h] * 512.0f + 2048.0f;
        s_W3[h] = W3[d * H_DIM + h];
    } else if (tid == 192) {
        s_b3 = b3[d];
    }
    // ---- stage W2^T as bf16 ----
    {
        const float* gW2 = W2 + (size_t)d * H_DIM * H_DIM;   // [h][col]
        #pragma unroll
        for (int i = 0; i < 16; ++i) {
            int idx = tid + i * 256;
            int h = idx >> 6, c = idx & 63;
            s_w2t[c * W2T_STRIDE + h] = f2bf(gW2[idx]);
        }
    }
    __syncthreads();

    // ---- x[n] = z[n,:] . softplus(W_mix[d,:]) ----
    const float4* zv = (const float4*)(z + (size_t)(nBase + tid) * L_DIM);
    float x = 0.0f;
    #pragma unroll
    for (int i = 0; i < 4; ++i) {
        float4 zz = zv[i];
        x += zz.x * s_mix[4*i+0] + zz.y * s_mix[4*i+1]
           + zz.z * s_mix[4*i+2] + zz.w * s_mix[4*i+3];
    }

    float xm[4];
    #pragma unroll
    for (int mt = 0; mt < 4; ++mt) xm[mt] = __shfl(x, mt * 16 + l15, 64);

    // ---- layer 1 -> A fragments via bf16 table: A[m=l15][k=quad*8+j] ----
    short8 afrag[4][2];
    #pragma unroll
    for (int ks = 0; ks < 2; ++ks) {
        float w1v[8], b1v[8];
        #pragma unroll
        for (int j = 0; j < 8; ++j) {
            int k = ks * 32 + quad * 8 + j;
            w1v[j] = s_w1s[k];
            b1v[j] = s_b1s[k];
        }
        #pragma unroll
        for (int mt = 0; mt < 4; ++mt) {
            unsigned short hb[8];
            #pragma unroll
            for (int j = 0; j < 8; ++j) {
                float idxf = fmaf(xm[mt], w1v[j], b1v[j]);
                idxf = fminf(fmaxf(idxf, 0.0f), 4095.0f);
                hb[j] = s_tabh[(unsigned int)idxf];
            }
            union { unsigned int u[4]; short8 s; } fr;
            #pragma unroll
            for (int p = 0; p < 4; ++p)
                fr.u[p] = (unsigned int)hb[2*p] | ((unsigned int)hb[2*p+1] << 16);
            afrag[mt][ks] = fr.s;
        }
    }

    // ---- B fragments from s_w2t ----
    short8 bfrag[4][2];
    #pragma unroll
    for (int nt = 0; nt < 4; ++nt)
        #pragma unroll
        for (int ks = 0; ks < 2; ++ks)
            bfrag[nt][ks] = *(const short8*)
                &s_w2t[(nt * 16 + l15) * W2T_STRIDE + ks * 32 + quad * 8];

    // ---- MFMA 4x4 tiles, K=64 ----
    float4v acc[4][4];
    #pragma unroll
    for (int mt = 0; mt < 4; ++mt)
        #pragma unroll
        for (int nt = 0; nt < 4; ++nt) {
            float4v c = {0.0f, 0.0f, 0.0f, 0.0f};
            c = __builtin_amdgcn_mfma_f32_16x16x32_bf16(afrag[mt][0], bfrag[nt][0], c, 0, 0, 0);
            c = __builtin_amdgcn_mfma_f32_16x16x32_bf16(afrag[mt][1], bfrag[nt][1], c, 0, 0, 0);
            acc[mt][nt] = c;
        }

    // ---- epilogue: psum = sum_col tanh_tab(acc + b2[col]) * W3[col] ----
    float w3v[4], c2v[4];
    #pragma unroll
    for (int nt = 0; nt < 4; ++nt) {
        int col = nt * 16 + l15;
        w3v[nt] = s_W3[col];
        c2v[nt] = s_c2[col];
    }

    float psum[4][4];
    #pragma unroll
    for (int mt = 0; mt < 4; ++mt)
        #pragma unroll
        for (int r = 0; r < 4; ++r) psum[mt][r] = 0.0f;

    #pragma unroll
    for (int mt = 0; mt < 4; ++mt)
        #pragma unroll
        for (int nt = 0; nt < 4; ++nt)
            #pragma unroll
            for (int r = 0; r < 4; ++r) {
                float idxf = fmaf(acc[mt][nt][r], 512.0f, c2v[nt]);
                idxf = fminf(fmaxf(idxf, 0.0f), 4095.0f);
                psum[mt][r] += s_tabf[(unsigned int)idxf] * w3v[nt];
            }

    #pragma unroll
    for (int mask = 1; mask < 16; mask <<= 1)
        #pragma unroll
        for (int mt = 0; mt < 4; ++mt)
            #pragma unroll
            for (int r = 0; r < 4; ++r)
                psum[mt][r] += __shfl_xor(psum[mt][r], mask, 64);

    const float bias = s_b3;
    #pragma unroll
    for (int mt = 0; mt < 4; ++mt)
        #pragma unroll
        for (int r = 0; r < 4; ++r)
            if (l15 == mt * 4 + r) {
                int row = mt * 16 + quad * 4 + r;
                int n = nBase + waveId * 64 + row;
                out[(size_t)n * D_DIM + d] = psum[mt][r] + bias;
            }
}

extern "C" void kernel_launch(void* const* d_in, const int* in_sizes, int n_in,
                              void* d_out, int out_size, void* d_ws, size_t ws_size,
                              hipStream_t stream) {
    const float* z     = (const float*)d_in[0];
    const float* W_mix = (const float*)d_in[1];
    const float* W1    = (const float*)d_in[2];
    const float* b1    = (const float*)d_in[3];
    const float* W2    = (const float*)d_in[4];
    const float* b2    = (const float*)d_in[5];
    const float* W3    = (const float*)d_in[6];
    const float* b3    = (const float*)d_in[7];
    float* out = (float*)d_out;

    const bool use_ws = (ws_size >= (size_t)(TAB_N * 4 + TAB_N * 2));
    float* tab = use_ws ? (float*)d_ws : nullptr;
    if (use_ws)
        build_tables<<<dim3(TAB_N / 256), dim3(256), 0, stream>>>(tab);

    dim3 grid(D_DIM, N_SAMPLES / 256);
    decoder_mfma<<<grid, dim3(256), 0, stream>>>(z, W_mix, W1, b1, W2, b2, W3, b3, out, tab);
}

// Round 4
// 101.433 us; speedup vs baseline: 3.4241x; 1.5834x over previous
//
#include <hip/hip_runtime.h>
#include <hip/hip_bf16.h>

// Decoder: x = z @ softplus(W_mix)^T ; per-channel MLP 1->H->H->1 with tanh.
// N=16384, L=16, D=128, H=64.
// Round 4 insight: out[n,d] = f_d(x[n,d]) -- the whole per-channel MLP is a
// scalar->scalar function. So: (1) build_f tabulates f_d on a 1/32-step grid
// over [-32,32] (2304 pts/channel) using the round-3 MFMA pipeline with x
// taken from the grid; (2) decode_lut computes x and linearly interpolates.
// x ~ N(0, 5.25^2) -> |x| < 23 << 32. Interp err = f''h^2/8 ~ 3e-3.
// decode_lut lanes are d-major -> coalesced 4B stores (round-3 wrote 64 MB
// of scattered stores; now 8.4 MB). Tables live in d_ws; fallback to the
// round-3 direct kernel if ws_size is too small.

#define N_SAMPLES 16384
#define L_DIM 16
#define D_DIM 128
#define H_DIM 64
#define W2T_STRIDE 72    // ushort elems; 144 B rows, 16B-aligned
#define TAB_N 4096       // tanh LUT: [-4,4], step 1/512
#define FT_PTS 2304      // f-table points per channel (9 blocks * 256)
#define FT_SCALE 32.0f   // idx = x*32 + 1024; step 1/32 over [-32,32]
#define FT_OFF 1024.0f
#define FT_BASE 6144     // f-table starts at ws[6144] (after 24 KB tanh LUTs)

typedef __attribute__((ext_vector_type(8))) short short8;
typedef __attribute__((ext_vector_type(4))) float float4v;

__device__ __forceinline__ float fast_tanh(float x) {
    float e = __expf(2.0f * x);
    return 1.0f - 2.0f * __builtin_amdgcn_rcpf(1.0f + e);
}

__device__ __forceinline__ unsigned short f2bf(float f) {
    union { float f; unsigned int u; } v; v.f = f;
    unsigned int r = (v.u + 0x7fffu + ((v.u >> 16) & 1u)) >> 16;   // RNE
    return (unsigned short)r;
}

__device__ __forceinline__ float softplus_f(float w) {
    return (w > 20.0f) ? w : log1pf(__expf(w));
}

// ---- tanh LUT builder: ws[0..4095] f32, then 4096 u16 bf16 at ws+4096 ----
__global__ void build_tables(float* __restrict__ ws) {
    int i = blockIdx.x * 256 + threadIdx.x;          // 0..4095
    float c = ((float)(i - 2048) + 0.5f) * (1.0f / 512.0f);
    float v = tanhf(c);
    ws[i] = v;
    ((unsigned short*)(ws + TAB_N))[i] = f2bf(v);
}

// =====================================================================
// build_f: tabulate f_d at grid points x = gi/32 - 32, gi in [0, 2304).
// Round-3 MFMA pipeline, x from grid formula (no z / W_mix involved).
// =====================================================================
__global__ __launch_bounds__(256, 2) void build_f(
    const float* __restrict__ W1,
    const float* __restrict__ b1,
    const float* __restrict__ W2,
    const float* __restrict__ b2,
    const float* __restrict__ W3,
    const float* __restrict__ b3,
    float* __restrict__ ftab,
    const float* __restrict__ tab_src)
{
    const int d      = blockIdx.x;
    const int tid    = threadIdx.x;
    const int lane   = tid & 63;
    const int waveId = tid >> 6;
    const int quad   = lane >> 4;
    const int l15    = lane & 15;
    const int gBase  = blockIdx.y * 256;

    __shared__ __align__(16) float s_w1s[H_DIM];   // 512*W1
    __shared__ __align__(16) float s_b1s[H_DIM];   // 512*b1 + 2048
    __shared__ float s_c2[H_DIM];                  // 512*b2 + 2048
    __shared__ float s_W3[H_DIM];
    __shared__ float s_b3;
    __shared__ __align__(16) unsigned short s_w2t[H_DIM * W2T_STRIDE];
    __shared__ __align__(16) float s_tabf[TAB_N];
    __shared__ __align__(16) unsigned short s_tabh[TAB_N];

    // stage tanh LUTs
    {
        const float4* g4 = (const float4*)tab_src;
        float4* sf4 = (float4*)s_tabf;
        #pragma unroll
        for (int i = 0; i < 4; ++i) sf4[tid + 256 * i] = g4[tid + 256 * i];
        const float4* g4h = (const float4*)(tab_src + TAB_N);
        float4* sh4 = (float4*)s_tabh;
        #pragma unroll
        for (int i = 0; i < 2; ++i) sh4[tid + 256 * i] = g4h[tid + 256 * i];
    }

    if (tid < 64) {
        s_w1s[tid] = W1[d * H_DIM + tid] * 512.0f;
        s_b1s[tid] = b1[d * H_DIM + tid] * 512.0f + 2048.0f;
    } else if (tid < 128) {
        int h = tid - 64;
        s_c2[h] = b2[d * H_DIM + h] * 512.0f + 2048.0f;
        s_W3[h] = W3[d * H_DIM + h];
    } else if (tid == 128) {
        s_b3 = b3[d];
    }
    {
        const float* gW2 = W2 + (size_t)d * H_DIM * H_DIM;   // [h][col]
        #pragma unroll
        for (int i = 0; i < 16; ++i) {
            int idx = tid + i * 256;
            int h = idx >> 6, c = idx & 63;
            s_w2t[c * W2T_STRIDE + h] = f2bf(gW2[idx]);
        }
    }
    __syncthreads();

    // grid-point x for this thread
    float x = (float)(gBase + tid) * (1.0f / FT_SCALE) - 32.0f;

    float xm[4];
    #pragma unroll
    for (int mt = 0; mt < 4; ++mt) xm[mt] = __shfl(x, mt * 16 + l15, 64);

    // layer 1 -> A fragments via bf16 tanh LUT
    short8 afrag[4][2];
    #pragma unroll
    for (int ks = 0; ks < 2; ++ks) {
        float w1v[8], b1v[8];
        #pragma unroll
        for (int j = 0; j < 8; ++j) {
            int k = ks * 32 + quad * 8 + j;
            w1v[j] = s_w1s[k];
            b1v[j] = s_b1s[k];
        }
        #pragma unroll
        for (int mt = 0; mt < 4; ++mt) {
            unsigned short hb[8];
            #pragma unroll
            for (int j = 0; j < 8; ++j) {
                float idxf = fmaf(xm[mt], w1v[j], b1v[j]);
                idxf = fminf(fmaxf(idxf, 0.0f), 4095.0f);
                hb[j] = s_tabh[(unsigned int)idxf];
            }
            union { unsigned int u[4]; short8 s; } fr;
            #pragma unroll
            for (int p = 0; p < 4; ++p)
                fr.u[p] = (unsigned int)hb[2*p] | ((unsigned int)hb[2*p+1] << 16);
            afrag[mt][ks] = fr.s;
        }
    }

    short8 bfrag[4][2];
    #pragma unroll
    for (int nt = 0; nt < 4; ++nt)
        #pragma unroll
        for (int ks = 0; ks < 2; ++ks)
            bfrag[nt][ks] = *(const short8*)
                &s_w2t[(nt * 16 + l15) * W2T_STRIDE + ks * 32 + quad * 8];

    float4v acc[4][4];
    #pragma unroll
    for (int mt = 0; mt < 4; ++mt)
        #pragma unroll
        for (int nt = 0; nt < 4; ++nt) {
            float4v c = {0.0f, 0.0f, 0.0f, 0.0f};
            c = __builtin_amdgcn_mfma_f32_16x16x32_bf16(afrag[mt][0], bfrag[nt][0], c, 0, 0, 0);
            c = __builtin_amdgcn_mfma_f32_16x16x32_bf16(afrag[mt][1], bfrag[nt][1], c, 0, 0, 0);
            acc[mt][nt] = c;
        }

    float w3v[4], c2v[4];
    #pragma unroll
    for (int nt = 0; nt < 4; ++nt) {
        int col = nt * 16 + l15;
        w3v[nt] = s_W3[col];
        c2v[nt] = s_c2[col];
    }

    float psum[4][4];
    #pragma unroll
    for (int mt = 0; mt < 4; ++mt)
        #pragma unroll
        for (int r = 0; r < 4; ++r) psum[mt][r] = 0.0f;

    #pragma unroll
    for (int mt = 0; mt < 4; ++mt)
        #pragma unroll
        for (int nt = 0; nt < 4; ++nt)
            #pragma unroll
            for (int r = 0; r < 4; ++r) {
                float idxf = fmaf(acc[mt][nt][r], 512.0f, c2v[nt]);
                idxf = fminf(fmaxf(idxf, 0.0f), 4095.0f);
                psum[mt][r] += s_tabf[(unsigned int)idxf] * w3v[nt];
            }

    #pragma unroll
    for (int mask = 1; mask < 16; mask <<= 1)
        #pragma unroll
        for (int mt = 0; mt < 4; ++mt)
            #pragma unroll
            for (int r = 0; r < 4; ++r)
                psum[mt][r] += __shfl_xor(psum[mt][r], mask, 64);

    const float bias = s_b3;
    #pragma unroll
    for (int mt = 0; mt < 4; ++mt)
        #pragma unroll
        for (int r = 0; r < 4; ++r)
            if (l15 == mt * 4 + r) {
                int row = mt * 16 + quad * 4 + r;
                int gi = gBase + waveId * 64 + row;
                ftab[d * FT_PTS + gi] = psum[mt][r] + bias;
            }
}

// =====================================================================
// decode_lut: x = z . softplus(W_mix[d]); out = lerp(ftab_d, x).
// Block = 32 samples x 128 channels; lanes d-major -> coalesced stores.
// =====================================================================
__global__ __launch_bounds__(256) void decode_lut(
    const float* __restrict__ z,
    const float* __restrict__ W_mix,
    const float* __restrict__ ftab,
    float* __restrict__ out)
{
    const int tid  = threadIdx.x;
    const int d    = tid & 127;
    const int half = tid >> 7;           // 0/1
    const int n0   = blockIdx.x * 32;

    __shared__ float sp_t[L_DIM][D_DIM]; // softplus(W_mix)^T, 8 KB
    __shared__ float z_s[32 * L_DIM];    // 2 KB

    #pragma unroll
    for (int i = 0; i < 8; ++i) {
        int idx = tid + i * 256;         // = dd*16 + l
        int dd = idx >> 4, l = idx & 15;
        sp_t[l][dd] = softplus_f(W_mix[idx]);
    }
    if (tid < 128)
        ((float4*)z_s)[tid] = ((const float4*)(z + (size_t)n0 * L_DIM))[tid];
    __syncthreads();

    const float* tab = ftab + d * FT_PTS;

    #pragma unroll
    for (int s = 0; s < 16; ++s) {
        int nsub = half * 16 + s;
        float x = 0.0f;
        #pragma unroll
        for (int l = 0; l < L_DIM; ++l)
            x = fmaf(z_s[nsub * L_DIM + l], sp_t[l][d], x);

        float idxf = fmaf(x, FT_SCALE, FT_OFF);
        idxf = fminf(fmaxf(idxf, 0.0f), 2047.0f);
        int i = (int)idxf;
        float fr = idxf - (float)i;
        float v0 = tab[i];
        float v1 = tab[i + 1];
        out[(size_t)(n0 + nsub) * D_DIM + d] = fmaf(v1 - v0, fr, v0);
    }
}

// =====================================================================
// Fallback: round-3 direct kernel (used only if ws_size is too small).
// =====================================================================
__global__ __launch_bounds__(256, 2) void decoder_direct(
    const float* __restrict__ z,
    const float* __restrict__ W_mix,
    const float* __restrict__ W1,
    const float* __restrict__ b1,
    const float* __restrict__ W2,
    const float* __restrict__ b2,
    const float* __restrict__ W3,
    const float* __restrict__ b3,
    float* __restrict__ out)
{
    const int d      = blockIdx.x;
    const int tid    = threadIdx.x;
    const int lane   = tid & 63;
    const int waveId = tid >> 6;
    const int quad   = lane >> 4;
    const int l15    = lane & 15;
    const int nBase  = blockIdx.y * 256;

    __shared__ float s_mix[L_DIM];
    __shared__ __align__(16) float s_w1s[H_DIM];
    __shared__ __align__(16) float s_b1s[H_DIM];
    __shared__ float s_c2[H_DIM];
    __shared__ float s_W3[H_DIM];
    __shared__ float s_b3;
    __shared__ __align__(16) unsigned short s_w2t[H_DIM * W2T_STRIDE];
    __shared__ __align__(16) float s_tabf[TAB_N];
    __shared__ __align__(16) unsigned short s_tabh[TAB_N];

    for (int i = tid; i < TAB_N; i += 256) {
        float c = ((float)(i - 2048) + 0.5f) * (1.0f / 512.0f);
        float v = fast_tanh(c);
        s_tabf[i] = v;
        s_tabh[i] = f2bf(v);
    }
    if (tid < L_DIM) {
        s_mix[tid] = softplus_f(W_mix[d * L_DIM + tid]);
    } else if (tid >= 64 && tid < 128) {
        int h = tid - 64;
        s_w1s[h] = W1[d * H_DIM + h] * 512.0f;
        s_b1s[h] = b1[d * H_DIM + h] * 512.0f + 2048.0f;
    } else if (tid >= 128 && tid < 192) {
        int h = tid - 128;
        s_c2[h] = b2[d * H_DIM + h] * 512.0f + 2048.0f;
        s_W3[h] = W3[d * H_DIM + h];
    } else if (tid == 192) {
        s_b3 = b3[d];
    }
    {
        const float* gW2 = W2 + (size_t)d * H_DIM * H_DIM;
        #pragma unroll
        for (int i = 0; i < 16; ++i) {
            int idx = tid + i * 256;
            int h = idx >> 6, c = idx & 63;
            s_w2t[c * W2T_STRIDE + h] = f2bf(gW2[idx]);
        }
    }
    __syncthreads();

    const float4* zv = (const float4*)(z + (size_t)(nBase + tid) * L_DIM);
    float x = 0.0f;
    #pragma unroll
    for (int i = 0; i < 4; ++i) {
        float4 zz = zv[i];
        x += zz.x * s_mix[4*i+0] + zz.y * s_mix[4*i+1]
           + zz.z * s_mix[4*i+2] + zz.w * s_mix[4*i+3];
    }

    float xm[4];
    #pragma unroll
    for (int mt = 0; mt < 4; ++mt) xm[mt] = __shfl(x, mt * 16 + l15, 64);

    short8 afrag[4][2];
    #pragma unroll
    for (int ks = 0; ks < 2; ++ks) {
        float w1v[8], b1v[8];
        #pragma unroll
        for (int j = 0; j < 8; ++j) {
            int k = ks * 32 + quad * 8 + j;
            w1v[j] = s_w1s[k];
            b1v[j] = s_b1s[k];
        }
        #pragma unroll
        for (int mt = 0; mt < 4; ++mt) {
            unsigned short hb[8];
            #pragma unroll
            for (int j = 0; j < 8; ++j) {
                float idxf = fmaf(xm[mt], w1v[j], b1v[j]);
                idxf = fminf(fmaxf(idxf, 0.0f), 4095.0f);
                hb[j] = s_tabh[(unsigned int)idxf];
            }
            union { unsigned int u[4]; short8 s; } fr;
            #pragma unroll
            for (int p = 0; p < 4; ++p)
                fr.u[p] = (unsigned int)hb[2*p] | ((unsigned int)hb[2*p+1] << 16);
            afrag[mt][ks] = fr.s;
        }
    }

    short8 bfrag[4][2];
    #pragma unroll
    for (int nt = 0; nt < 4; ++nt)
        #pragma unroll
        for (int ks = 0; ks < 2; ++ks)
            bfrag[nt][ks] = *(const short8*)
                &s_w2t[(nt * 16 + l15) * W2T_STRIDE + ks * 32 + quad * 8];

    float4v acc[4][4];
    #pragma unroll
    for (int mt = 0; mt < 4; ++mt)
        #pragma unroll
        for (int nt = 0; nt < 4; ++nt) {
            float4v c = {0.0f, 0.0f, 0.0f, 0.0f};
            c = __builtin_amdgcn_mfma_f32_16x16x32_bf16(afrag[mt][0], bfrag[nt][0], c, 0, 0, 0);
            c = __builtin_amdgcn_mfma_f32_16x16x32_bf16(afrag[mt][1], bfrag[nt][1], c, 0, 0, 0);
            acc[mt][nt] = c;
        }

    float w3v[4], c2v[4];
    #pragma unroll
    for (int nt = 0; nt < 4; ++nt) {
        int col = nt * 16 + l15;
        w3v[nt] = s_W3[col];
        c2v[nt] = s_c2[col];
    }

    float psum[4][4];
    #pragma unroll
    for (int mt = 0; mt < 4; ++mt)
        #pragma unroll
        for (int r = 0; r < 4; ++r) psum[mt][r] = 0.0f;

    #pragma unroll
    for (int mt = 0; mt < 4; ++mt)
        #pragma unroll
        for (int nt = 0; nt < 4; ++nt)
            #pragma unroll
            for (int r = 0; r < 4; ++r) {
                float idxf = fmaf(acc[mt][nt][r], 512.0f, c2v[nt]);
                idxf = fminf(fmaxf(idxf, 0.0f), 4095.0f);
                psum[mt][r] += s_tabf[(unsigned int)idxf] * w3v[nt];
            }

    #pragma unroll
    for (int mask = 1; mask < 16; mask <<= 1)
        #pragma unroll
        for (int mt = 0; mt < 4; ++mt)
            #pragma unroll
            for (int r = 0; r < 4; ++r)
                psum[mt][r] += __shfl_xor(psum[mt][r], mask, 64);

    const float bias = s_b3;
    #pragma unroll
    for (int mt = 0; mt < 4; ++mt)
        #pragma unroll
        for (int r = 0; r < 4; ++r)
            if (l15 == mt * 4 + r) {
                int row = mt * 16 + quad * 4 + r;
                int n = nBase + waveId * 64 + row;
                out[(size_t)n * D_DIM + d] = psum[mt][r] + bias;
            }
}

extern "C" void kernel_launch(void* const* d_in, const int* in_sizes, int n_in,
                              void* d_out, int out_size, void* d_ws, size_t ws_size,
                              hipStream_t stream) {
    const float* z     = (const float*)d_in[0];
    const float* W_mix = (const float*)d_in[1];
    const float* W1    = (const float*)d_in[2];
    const float* b1    = (const float*)d_in[3];
    const float* W2    = (const float*)d_in[4];
    const float* b2    = (const float*)d_in[5];
    const float* W3    = (const float*)d_in[6];
    const float* b3    = (const float*)d_in[7];
    float* out = (float*)d_out;
    float* ws  = (float*)d_ws;

    const size_t need = (size_t)(FT_BASE + D_DIM * FT_PTS) * 4;
    if (ws_size >= need) {
        build_tables<<<dim3(TAB_N / 256), dim3(256), 0, stream>>>(ws);
        float* ftab = ws + FT_BASE;
        build_f<<<dim3(D_DIM, FT_PTS / 256), dim3(256), 0, stream>>>(
            W1, b1, W2, b2, W3, b3, ftab, ws);
        decode_lut<<<dim3(N_SAMPLES / 32), dim3(256), 0, stream>>>(
            z, W_mix, ftab, out);
    } else {
        dim3 grid(D_DIM, N_SAMPLES / 256);
        decoder_direct<<<grid, dim3(256), 0, stream>>>(
            z, W_mix, W1, b1, W2, b2, W3, b3, out);
    }
}

// Round 5
// 90.225 us; speedup vs baseline: 3.8494x; 1.1242x over previous
//
#include <hip/hip_runtime.h>
#include <hip/hip_bf16.h>

// Decoder: x = z @ softplus(W_mix)^T ; per-channel MLP 1->H->H->1 with tanh.
// N=16384, L=16, D=128, H=64.
// Round 5: out[n,d] = f_d(x[n,d]) scalar-function factorization (round 4),
// with the serial chain shortened to TWO kernels:
//   build_f : tabulates f_d at 1280 pts (step 1/16 over [-40,40)) via the
//             MFMA pipeline; builds tanh LUTs in-LDS (no build_tables
//             kernel); first 8 blocks also write softplus(W_mix) to ws.
//   decode  : x = z . sp[d]; linear interp from ftab; coalesced stores.
// Round-4 counters showed the harness ws-poison (268 MB fill, ~41 us) is
// the floor; controllable work is build_f+decode+gaps. Step 1/16 is safe:
// |f''| = O(1-3) -> interp err ~2e-3; measured headroom 0.03.

#define N_SAMPLES 16384
#define L_DIM 16
#define D_DIM 128
#define H_DIM 64
#define W2T_STRIDE 72    // ushort elems; 144 B rows, 16B-aligned
#define TAB_N 4096       // tanh LUT: [-4,4], step 1/512
#define FT_PTS 1280      // f-table points per channel (5 blocks * 256)
#define FT_SCALE 16.0f   // idx = x*16 + 640; step 1/16 over [-40,40)
#define FT_OFF 640.0f
#define SP_N (D_DIM * L_DIM)   // 2048 softplus(W_mix) values, layout [d][l]
#define FT_BASE SP_N           // ftab starts at ws[2048]

typedef __attribute__((ext_vector_type(8))) short short8;
typedef __attribute__((ext_vector_type(4))) float float4v;

__device__ __forceinline__ float fast_tanh(float x) {
    float e = __expf(2.0f * x);
    return 1.0f - 2.0f * __builtin_amdgcn_rcpf(1.0f + e);
}

__device__ __forceinline__ unsigned short f2bf(float f) {
    union { float f; unsigned int u; } v; v.f = f;
    unsigned int r = (v.u + 0x7fffu + ((v.u >> 16) & 1u)) >> 16;   // RNE
    return (unsigned short)r;
}

__device__ __forceinline__ float softplus_f(float w) {
    return (w > 20.0f) ? w : log1pf(__expf(w));
}

// =====================================================================
// build_f: tabulate f_d at x = gi/16 - 40, gi in [0,1280). Block =
// (d, 256-point tile), 4 waves. tanh LUTs built in-LDS. Blocks with
// gBase==0 && d<8 also write softplus(W_mix) to ws (sp, layout [d][l]).
// =====================================================================
__global__ __launch_bounds__(256, 2) void build_f(
    const float* __restrict__ W_mix,
    const float* __restrict__ W1,
    const float* __restrict__ b1,
    const float* __restrict__ W2,
    const float* __restrict__ b2,
    const float* __restrict__ W3,
    const float* __restrict__ b3,
    float* __restrict__ ws)          // [0..2047]=sp, [2048..]=ftab
{
    const int d      = blockIdx.x;
    const int tid    = threadIdx.x;
    const int lane   = tid & 63;
    const int waveId = tid >> 6;
    const int quad   = lane >> 4;
    const int l15    = lane & 15;
    const int gBase  = blockIdx.y * 256;

    __shared__ __align__(16) float s_w1s[H_DIM];   // 512*W1
    __shared__ __align__(16) float s_b1s[H_DIM];   // 512*b1 + 2048
    __shared__ float s_c2[H_DIM];                  // 512*b2 + 2048
    __shared__ float s_W3[H_DIM];
    __shared__ float s_b3;
    __shared__ __align__(16) unsigned short s_w2t[H_DIM * W2T_STRIDE];
    __shared__ __align__(16) float s_tabf[TAB_N];          // 16 KB
    __shared__ __align__(16) unsigned short s_tabh[TAB_N]; // 8 KB

    // in-block tanh LUT build (16 evals/thread)
    #pragma unroll
    for (int it = 0; it < TAB_N / 256; ++it) {
        int i = tid + it * 256;
        float c = ((float)(i - 2048) + 0.5f) * (1.0f / 512.0f);
        float v = fast_tanh(c);
        s_tabf[i] = v;
        s_tabh[i] = f2bf(v);
    }

    // softplus(W_mix) sidecar write (first 8 y0-blocks cover 2048 values)
    if (gBase == 0 && d < 8)
        ws[d * 256 + tid] = softplus_f(W_mix[d * 256 + tid]);

    if (tid < 64) {
        s_w1s[tid] = W1[d * H_DIM + tid] * 512.0f;
        s_b1s[tid] = b1[d * H_DIM + tid] * 512.0f + 2048.0f;
    } else if (tid < 128) {
        int h = tid - 64;
        s_c2[h] = b2[d * H_DIM + h] * 512.0f + 2048.0f;
        s_W3[h] = W3[d * H_DIM + h];
    } else if (tid == 128) {
        s_b3 = b3[d];
    }
    {
        const float* gW2 = W2 + (size_t)d * H_DIM * H_DIM;   // [h][col]
        #pragma unroll
        for (int i = 0; i < 16; ++i) {
            int idx = tid + i * 256;
            int h = idx >> 6, c = idx & 63;
            s_w2t[c * W2T_STRIDE + h] = f2bf(gW2[idx]);
        }
    }
    __syncthreads();

    // grid-point x for this thread
    float x = (float)(gBase + tid) * (1.0f / FT_SCALE) - 40.0f;

    float xm[4];
    #pragma unroll
    for (int mt = 0; mt < 4; ++mt) xm[mt] = __shfl(x, mt * 16 + l15, 64);

    // layer 1 -> A fragments via bf16 tanh LUT: A[m=l15][k=quad*8+j]
    short8 afrag[4][2];
    #pragma unroll
    for (int ks = 0; ks < 2; ++ks) {
        float w1v[8], b1v[8];
        #pragma unroll
        for (int j = 0; j < 8; ++j) {
            int k = ks * 32 + quad * 8 + j;
            w1v[j] = s_w1s[k];
            b1v[j] = s_b1s[k];
        }
        #pragma unroll
        for (int mt = 0; mt < 4; ++mt) {
            unsigned short hb[8];
            #pragma unroll
            for (int j = 0; j < 8; ++j) {
                float idxf = fmaf(xm[mt], w1v[j], b1v[j]);
                idxf = fminf(fmaxf(idxf, 0.0f), 4095.0f);
                hb[j] = s_tabh[(unsigned int)idxf];
            }
            union { unsigned int u[4]; short8 s; } fr;
            #pragma unroll
            for (int p = 0; p < 4; ++p)
                fr.u[p] = (unsigned int)hb[2*p] | ((unsigned int)hb[2*p+1] << 16);
            afrag[mt][ks] = fr.s;
        }
    }

    short8 bfrag[4][2];
    #pragma unroll
    for (int nt = 0; nt < 4; ++nt)
        #pragma unroll
        for (int ks = 0; ks < 2; ++ks)
            bfrag[nt][ks] = *(const short8*)
                &s_w2t[(nt * 16 + l15) * W2T_STRIDE + ks * 32 + quad * 8];

    float4v acc[4][4];
    #pragma unroll
    for (int mt = 0; mt < 4; ++mt)
        #pragma unroll
        for (int nt = 0; nt < 4; ++nt) {
            float4v c = {0.0f, 0.0f, 0.0f, 0.0f};
            c = __builtin_amdgcn_mfma_f32_16x16x32_bf16(afrag[mt][0], bfrag[nt][0], c, 0, 0, 0);
            c = __builtin_amdgcn_mfma_f32_16x16x32_bf16(afrag[mt][1], bfrag[nt][1], c, 0, 0, 0);
            acc[mt][nt] = c;
        }

    float w3v[4], c2v[4];
    #pragma unroll
    for (int nt = 0; nt < 4; ++nt) {
        int col = nt * 16 + l15;
        w3v[nt] = s_W3[col];
        c2v[nt] = s_c2[col];
    }

    float psum[4][4];
    #pragma unroll
    for (int mt = 0; mt < 4; ++mt)
        #pragma unroll
        for (int r = 0; r < 4; ++r) psum[mt][r] = 0.0f;

    #pragma unroll
    for (int mt = 0; mt < 4; ++mt)
        #pragma unroll
        for (int nt = 0; nt < 4; ++nt)
            #pragma unroll
            for (int r = 0; r < 4; ++r) {
                float idxf = fmaf(acc[mt][nt][r], 512.0f, c2v[nt]);
                idxf = fminf(fmaxf(idxf, 0.0f), 4095.0f);
                psum[mt][r] += s_tabf[(unsigned int)idxf] * w3v[nt];
            }

    #pragma unroll
    for (int mask = 1; mask < 16; mask <<= 1)
        #pragma unroll
        for (int mt = 0; mt < 4; ++mt)
            #pragma unroll
            for (int r = 0; r < 4; ++r)
                psum[mt][r] += __shfl_xor(psum[mt][r], mask, 64);

    const float bias = s_b3;
    float* ftab = ws + FT_BASE;
    #pragma unroll
    for (int mt = 0; mt < 4; ++mt)
        #pragma unroll
        for (int r = 0; r < 4; ++r)
            if (l15 == mt * 4 + r) {
                int row = mt * 16 + quad * 4 + r;
                int gi = gBase + waveId * 64 + row;
                ftab[d * FT_PTS + gi] = psum[mt][r] + bias;
            }
}

// =====================================================================
// decode_lut: x = z . sp[d]; out = lerp(ftab_d, x). Block = 32 samples x
// 128 channels; lane = d-major -> coalesced stores. sp ([d][l]) hoisted
// into 4 float4 regs per thread; z read as float4 from LDS.
// =====================================================================
__global__ __launch_bounds__(256) void decode_lut(
    const float* __restrict__ z,
    const float* __restrict__ ws,
    float* __restrict__ out)
{
    const int tid  = threadIdx.x;
    const int d    = tid & 127;
    const int half = tid >> 7;           // 0/1
    const int n0   = blockIdx.x * 32;

    __shared__ __align__(16) float s_sp[SP_N];     // [d][l], 8 KB
    __shared__ __align__(16) float s_z[32 * L_DIM]; // 2 KB

    ((float4*)s_sp)[tid]       = ((const float4*)ws)[tid];
    ((float4*)s_sp)[tid + 256] = ((const float4*)ws)[tid + 256];
    if (tid < 128)
        ((float4*)s_z)[tid] = ((const float4*)(z + (size_t)n0 * L_DIM))[tid];
    __syncthreads();

    float4 spv[4];
    #pragma unroll
    for (int i = 0; i < 4; ++i) spv[i] = ((const float4*)(s_sp + d * L_DIM))[i];

    const float* tab = ws + FT_BASE + d * FT_PTS;
    const float4* zq = (const float4*)s_z;

    #pragma unroll
    for (int s = 0; s < 16; ++s) {
        int nsub = half * 16 + s;
        float x = 0.0f;
        #pragma unroll
        for (int i = 0; i < 4; ++i) {
            float4 zz = zq[nsub * 4 + i];
            x = fmaf(zz.x, spv[i].x, x);
            x = fmaf(zz.y, spv[i].y, x);
            x = fmaf(zz.z, spv[i].z, x);
            x = fmaf(zz.w, spv[i].w, x);
        }
        float idxf = fmaf(x, FT_SCALE, FT_OFF);
        idxf = fminf(fmaxf(idxf, 0.0f), (float)(FT_PTS - 2));
        int i = (int)idxf;
        float fr = idxf - (float)i;
        float v0 = tab[i];
        float v1 = tab[i + 1];
        out[(size_t)(n0 + nsub) * D_DIM + d] = fmaf(v1 - v0, fr, v0);
    }
}

// =====================================================================
// Fallback: direct kernel (only if ws_size is too small).
// =====================================================================
__global__ __launch_bounds__(256, 2) void decoder_direct(
    const float* __restrict__ z,
    const float* __restrict__ W_mix,
    const float* __restrict__ W1,
    const float* __restrict__ b1,
    const float* __restrict__ W2,
    const float* __restrict__ b2,
    const float* __restrict__ W3,
    const float* __restrict__ b3,
    float* __restrict__ out)
{
    const int d      = blockIdx.x;
    const int tid    = threadIdx.x;
    const int lane   = tid & 63;
    const int waveId = tid >> 6;
    const int quad   = lane >> 4;
    const int l15    = lane & 15;
    const int nBase  = blockIdx.y * 256;

    __shared__ float s_mix[L_DIM];
    __shared__ __align__(16) float s_w1s[H_DIM];
    __shared__ __align__(16) float s_b1s[H_DIM];
    __shared__ float s_c2[H_DIM];
    __shared__ float s_W3[H_DIM];
    __shared__ float s_b3;
    __shared__ __align__(16) unsigned short s_w2t[H_DIM * W2T_STRIDE];
    __shared__ __align__(16) float s_tabf[TAB_N];
    __shared__ __align__(16) unsigned short s_tabh[TAB_N];

    for (int i = tid; i < TAB_N; i += 256) {
        float c = ((float)(i - 2048) + 0.5f) * (1.0f / 512.0f);
        float v = fast_tanh(c);
        s_tabf[i] = v;
        s_tabh[i] = f2bf(v);
    }
    if (tid < L_DIM) {
        s_mix[tid] = softplus_f(W_mix[d * L_DIM + tid]);
    } else if (tid >= 64 && tid < 128) {
        int h = tid - 64;
        s_w1s[h] = W1[d * H_DIM + h] * 512.0f;
        s_b1s[h] = b1[d * H_DIM + h] * 512.0f + 2048.0f;
    } else if (tid >= 128 && tid < 192) {
        int h = tid - 128;
        s_c2[h] = b2[d * H_DIM + h] * 512.0f + 2048.0f;
        s_W3[h] = W3[d * H_DIM + h];
    } else if (tid == 192) {
        s_b3 = b3[d];
    }
    {
        const float* gW2 = W2 + (size_t)d * H_DIM * H_DIM;
        #pragma unroll
        for (int i = 0; i < 16; ++i) {
            int idx = tid + i * 256;
            int h = idx >> 6, c = idx & 63;
            s_w2t[c * W2T_STRIDE + h] = f2bf(gW2[idx]);
        }
    }
    __syncthreads();

    const float4* zv = (const float4*)(z + (size_t)(nBase + tid) * L_DIM);
    float x = 0.0f;
    #pragma unroll
    for (int i = 0; i < 4; ++i) {
        float4 zz = zv[i];
        x += zz.x * s_mix[4*i+0] + zz.y * s_mix[4*i+1]
           + zz.z * s_mix[4*i+2] + zz.w * s_mix[4*i+3];
    }

    float xm[4];
    #pragma unroll
    for (int mt = 0; mt < 4; ++mt) xm[mt] = __shfl(x, mt * 16 + l15, 64);

    short8 afrag[4][2];
    #pragma unroll
    for (int ks = 0; ks < 2; ++ks) {
        float w1v[8], b1v[8];
        #pragma unroll
        for (int j = 0; j < 8; ++j) {
            int k = ks * 32 + quad * 8 + j;
            w1v[j] = s_w1s[k];
            b1v[j] = s_b1s[k];
        }
        #pragma unroll
        for (int mt = 0; mt < 4; ++mt) {
            unsigned short hb[8];
            #pragma unroll
            for (int j = 0; j < 8; ++j) {
                float idxf = fmaf(xm[mt], w1v[j], b1v[j]);
                idxf = fminf(fmaxf(idxf, 0.0f), 4095.0f);
                hb[j] = s_tabh[(unsigned int)idxf];
            }
            union { unsigned int u[4]; short8 s; } fr;
            #pragma unroll
            for (int p = 0; p < 4; ++p)
                fr.u[p] = (unsigned int)hb[2*p] | ((unsigned int)hb[2*p+1] << 16);
            afrag[mt][ks] = fr.s;
        }
    }

    short8 bfrag[4][2];
    #pragma unroll
    for (int nt = 0; nt < 4; ++nt)
        #pragma unroll
        for (int ks = 0; ks < 2; ++ks)
            bfrag[nt][ks] = *(const short8*)
                &s_w2t[(nt * 16 + l15) * W2T_STRIDE + ks * 32 + quad * 8];

    float4v acc[4][4];
    #pragma unroll
    for (int mt = 0; mt < 4; ++mt)
        #pragma unroll
        for (int nt = 0; nt < 4; ++nt) {
            float4v c = {0.0f, 0.0f, 0.0f, 0.0f};
            c = __builtin_amdgcn_mfma_f32_16x16x32_bf16(afrag[mt][0], bfrag[nt][0], c, 0, 0, 0);
            c = __builtin_amdgcn_mfma_f32_16x16x32_bf16(afrag[mt][1], bfrag[nt][1], c, 0, 0, 0);
            acc[mt][nt] = c;
        }

    float w3v[4], c2v[4];
    #pragma unroll
    for (int nt = 0; nt < 4; ++nt) {
        int col = nt * 16 + l15;
        w3v[nt] = s_W3[col];
        c2v[nt] = s_c2[col];
    }

    float psum[4][4];
    #pragma unroll
    for (int mt = 0; mt < 4; ++mt)
        #pragma unroll
        for (int r = 0; r < 4; ++r) psum[mt][r] = 0.0f;

    #pragma unroll
    for (int mt = 0; mt < 4; ++mt)
        #pragma unroll
        for (int nt = 0; nt < 4; ++nt)
            #pragma unroll
            for (int r = 0; r < 4; ++r) {
                float idxf = fmaf(acc[mt][nt][r], 512.0f, c2v[nt]);
                idxf = fminf(fmaxf(idxf, 0.0f), 4095.0f);
                psum[mt][r] += s_tabf[(unsigned int)idxf] * w3v[nt];
            }

    #pragma unroll
    for (int mask = 1; mask < 16; mask <<= 1)
        #pragma unroll
        for (int mt = 0; mt < 4; ++mt)
            #pragma unroll
            for (int r = 0; r < 4; ++r)
                psum[mt][r] += __shfl_xor(psum[mt][r], mask, 64);

    const float bias = s_b3;
    #pragma unroll
    for (int mt = 0; mt < 4; ++mt)
        #pragma unroll
        for (int r = 0; r < 4; ++r)
            if (l15 == mt * 4 + r) {
                int row = mt * 16 + quad * 4 + r;
                int n = nBase + waveId * 64 + row;
                out[(size_t)n * D_DIM + d] = psum[mt][r] + bias;
            }
}

extern "C" void kernel_launch(void* const* d_in, const int* in_sizes, int n_in,
                              void* d_out, int out_size, void* d_ws, size_t ws_size,
                              hipStream_t stream) {
    const float* z     = (const float*)d_in[0];
    const float* W_mix = (const float*)d_in[1];
    const float* W1    = (const float*)d_in[2];
    const float* b1    = (const float*)d_in[3];
    const float* W2    = (const float*)d_in[4];
    const float* b2    = (const float*)d_in[5];
    const float* W3    = (const float*)d_in[6];
    const float* b3    = (const float*)d_in[7];
    float* out = (float*)d_out;
    float* ws  = (float*)d_ws;

    const size_t need = (size_t)(FT_BASE + D_DIM * FT_PTS) * 4;
    if (ws_size >= need) {
        build_f<<<dim3(D_DIM, FT_PTS / 256), dim3(256), 0, stream>>>(
            W_mix, W1, b1, W2, b2, W3, b3, ws);
        decode_lut<<<dim3(N_SAMPLES / 32), dim3(256), 0, stream>>>(z, ws, out);
    } else {
        dim3 grid(D_DIM, N_SAMPLES / 256);
        decoder_direct<<<grid, dim3(256), 0, stream>>>(
            z, W_mix, W1, b1, W2, b2, W3, b3, out);
    }
}